// Round 1
// baseline (366.444 us; speedup 1.0000x reference)
//
#include <hip/hip_runtime.h>
#include <math.h>

// Chamfer distance, B=4, N=M=8192, fp32.
// Output layout (flat float32): dist1[B*N], dist2[B*M], idx1[B*N] (as float),
// idx2[B*M] (as float) — harness reads the whole buffer as float32 and splits.

#define TILE 2048  // LDS tile of the "reference" cloud: 2048*3*4 = 24 KB

__global__ __launch_bounds__(256) void chamfer_kernel(
    const float* __restrict__ xyz1, const float* __restrict__ xyz2,
    float* __restrict__ out, int N, int M, int B)
{
#pragma clang fp contract(off)  // match numpy per-op IEEE rounding (no fma fuse)
    const int dir = blockIdx.z;          // 0: xyz1->xyz2, 1: xyz2->xyz1
    const float* q = dir ? xyz2 : xyz1;  // query cloud
    const float* r = dir ? xyz1 : xyz2;  // reference cloud
    const int Nq = dir ? M : N;
    const int Nr = dir ? N : M;
    const int b = blockIdx.y;
    const int i = blockIdx.x * blockDim.x + threadIdx.x;

    float* dist_out = out + (dir ? (size_t)B * N : 0);
    float* idx_out  = out + (size_t)B * N + (size_t)B * M + (dir ? (size_t)B * N : 0);

    __shared__ float s[TILE * 3];

    float qx = 0.f, qy = 0.f, qz = 0.f;
    if (i < Nq) {
        const float* qp = q + ((size_t)b * Nq + i) * 3;
        qx = qp[0]; qy = qp[1]; qz = qp[2];
    }

    // 4 independent accumulators to break the dependent min/argmin chain.
    float bd0 = INFINITY, bd1 = INFINITY, bd2 = INFINITY, bd3 = INFINITY;
    int   bi0 = 0, bi1 = 1, bi2 = 2, bi3 = 3;

    for (int t0 = 0; t0 < Nr; t0 += TILE) {
        const int cnt = min(TILE, Nr - t0);
        __syncthreads();
        // cooperative coalesced load of the tile (flat xyzxyz... layout)
        for (int j = threadIdx.x; j < cnt * 3; j += blockDim.x)
            s[j] = r[((size_t)b * Nr + t0) * 3 + j];
        __syncthreads();

        int j = 0;
        for (; j + 3 < cnt; j += 4) {
            // all lanes read the same LDS word -> broadcast, conflict-free
            float dx0 = qx - s[3*j+0],  dy0 = qy - s[3*j+1],  dz0 = qz - s[3*j+2];
            float dx1 = qx - s[3*j+3],  dy1 = qy - s[3*j+4],  dz1 = qz - s[3*j+5];
            float dx2 = qx - s[3*j+6],  dy2 = qy - s[3*j+7],  dz2 = qz - s[3*j+8];
            float dx3 = qx - s[3*j+9],  dy3 = qy - s[3*j+10], dz3 = qz - s[3*j+11];
            float d0 = dx0*dx0 + dy0*dy0 + dz0*dz0;  // ((x+y)+z), per-op rn
            float d1 = dx1*dx1 + dy1*dy1 + dz1*dz1;
            float d2 = dx2*dx2 + dy2*dy2 + dz2*dz2;
            float d3 = dx3*dx3 + dy3*dy3 + dz3*dz3;
            if (d0 < bd0) { bd0 = d0; bi0 = t0 + j + 0; }
            if (d1 < bd1) { bd1 = d1; bi1 = t0 + j + 1; }
            if (d2 < bd2) { bd2 = d2; bi2 = t0 + j + 2; }
            if (d3 < bd3) { bd3 = d3; bi3 = t0 + j + 3; }
        }
        for (; j < cnt; ++j) {  // tail (unused for 8192/2048, kept for safety)
            float dx = qx - s[3*j+0], dy = qy - s[3*j+1], dz = qz - s[3*j+2];
            float d = dx*dx + dy*dy + dz*dz;
            if (d < bd0) { bd0 = d; bi0 = t0 + j; }
        }
    }

    // merge accumulators; tie-break on lower index = first occurrence (np.argmin)
    if (bd1 < bd0 || (bd1 == bd0 && bi1 < bi0)) { bd0 = bd1; bi0 = bi1; }
    if (bd3 < bd2 || (bd3 == bd2 && bi3 < bi2)) { bd2 = bd3; bi2 = bi3; }
    if (bd2 < bd0 || (bd2 == bd0 && bi2 < bi0)) { bd0 = bd2; bi0 = bi2; }

    if (i < Nq) {
        dist_out[(size_t)b * Nq + i] = bd0;
        idx_out[(size_t)b * Nq + i]  = (float)bi0;  // harness compares as float32
    }
}

extern "C" void kernel_launch(void* const* d_in, const int* in_sizes, int n_in,
                              void* d_out, int out_size, void* d_ws, size_t ws_size,
                              hipStream_t stream) {
    const float* xyz1 = (const float*)d_in[0];
    const float* xyz2 = (const float*)d_in[1];
    float* out = (float*)d_out;
    const int B = 4;
    const int N = in_sizes[0] / (B * 3);
    const int M = in_sizes[1] / (B * 3);
    const int NQ = (N > M ? N : M);
    dim3 grid((NQ + 255) / 256, B, 2);
    chamfer_kernel<<<grid, dim3(256, 1, 1), 0, stream>>>(xyz1, xyz2, out, N, M, B);
}

// Round 2
// 180.533 us; speedup vs baseline: 2.0298x; 2.0298x over previous
//
#include <hip/hip_runtime.h>
#include <math.h>

// Chamfer distance, B=4, N=M=8192, fp32.
// Output layout (flat float32): dist1[B*N], dist2[B*M], idx1[B*N] (as float),
// idx2[B*M] (as float).
//
// R1: split reference dim into S segments (partials in d_ws) for occupancy;
// 4 queries per thread to amortize LDS broadcast reads (3x ds_read_b128
// serve 16 distance evals). Merge kernel combines splits (ascending order +
// strict < == first-occurrence argmin, matching np.argmin).

#define QPT 4         // queries per thread
#define BLK 256       // threads per block
#define QPB (QPT*BLK) // queries per block = 1024

__global__ __launch_bounds__(256, 4) void chamfer_main(
    const float* __restrict__ xyz1, const float* __restrict__ xyz2,
    float* __restrict__ pd, int* __restrict__ pi,
    int N, int M, int B, int S, int C)
{
#pragma clang fp contract(off)  // match numpy per-op IEEE rounding (no fma fuse)
    const int dir = blockIdx.z;          // 0: xyz1->xyz2, 1: xyz2->xyz1
    const float* q = dir ? xyz2 : xyz1;  // query cloud
    const float* r = dir ? xyz1 : xyz2;  // reference cloud
    const int Nq = dir ? M : N;
    const int Nr = dir ? N : M;
    const int b     = blockIdx.y / S;
    const int split = blockIdx.y % S;
    const int base  = split * C;         // this block's ref-index range [base, base+C)

    extern __shared__ float s[];         // C*3 floats

    // cooperative vectorized tile load (alignment: C%4==0 -> 16B aligned)
    {
        const float4* gv = (const float4*)(r + ((size_t)b * Nr + base) * 3);
        float4* sv = (float4*)s;
        const int elems4 = C * 3 / 4;
        for (int t = threadIdx.x; t < elems4; t += BLK) sv[t] = gv[t];
    }
    __syncthreads();

    // load 4 query points (stride-BLK within the block's query window)
    float qx[QPT], qy[QPT], qz[QPT];
    int qi[QPT];
    bool qv[QPT];
#pragma unroll
    for (int k = 0; k < QPT; ++k) {
        qi[k] = blockIdx.x * QPB + k * BLK + threadIdx.x;
        qv[k] = qi[k] < Nq;
        const float* qp = q + ((size_t)b * Nq + (qv[k] ? qi[k] : 0)) * 3;
        qx[k] = qp[0]; qy[k] = qp[1]; qz[k] = qp[2];
    }

    // 4 ref-phase accumulators per query: 16 independent min/argmin chains
    float bd[QPT][4];
    int   bi[QPT][4];
#pragma unroll
    for (int k = 0; k < QPT; ++k)
#pragma unroll
        for (int p = 0; p < 4; ++p) { bd[k][p] = INFINITY; bi[k][p] = base + p; }

    const float4* sv = (const float4*)s;
    const int iters = C / 4;
    for (int j4 = 0; j4 < iters; ++j4) {
        // 12 floats = 4 ref points; all lanes same address -> LDS broadcast
        float4 f0 = sv[3 * j4 + 0];
        float4 f1 = sv[3 * j4 + 1];
        float4 f2 = sv[3 * j4 + 2];
        float px[4] = { f0.x, f0.w, f1.z, f2.y };
        float py[4] = { f0.y, f1.x, f1.w, f2.z };
        float pz[4] = { f0.z, f1.y, f2.x, f2.w };
        const int jb = base + 4 * j4;
#pragma unroll
        for (int p = 0; p < 4; ++p) {
#pragma unroll
            for (int k = 0; k < QPT; ++k) {
                float dx = qx[k] - px[p];
                float dy = qy[k] - py[p];
                float dz = qz[k] - pz[p];
                float d = dx * dx + dy * dy + dz * dz;  // ((x+y)+z), per-op rn
                if (d < bd[k][p]) { bd[k][p] = d; bi[k][p] = jb + p; }
            }
        }
    }

    // merge 4 phases per query; tie-break on lower index (first occurrence)
    const size_t pbase = ((size_t)(dir * B + b) * S + split) * Nq;
#pragma unroll
    for (int k = 0; k < QPT; ++k) {
        float d0 = bd[k][0]; int i0 = bi[k][0];
        float d1 = bd[k][1]; int i1 = bi[k][1];
        float d2 = bd[k][2]; int i2 = bi[k][2];
        float d3 = bd[k][3]; int i3 = bi[k][3];
        if (d1 < d0 || (d1 == d0 && i1 < i0)) { d0 = d1; i0 = i1; }
        if (d3 < d2 || (d3 == d2 && i3 < i2)) { d2 = d3; i2 = i3; }
        if (d2 < d0 || (d2 == d0 && i2 < i0)) { d0 = d2; i0 = i2; }
        if (qv[k]) {
            pd[pbase + qi[k]] = d0;
            pi[pbase + qi[k]] = i0;
        }
    }
}

__global__ __launch_bounds__(256) void chamfer_merge(
    const float* __restrict__ pd, const int* __restrict__ pi,
    float* __restrict__ out, int N, int M, int B, int S)
{
    const int gid = blockIdx.x * blockDim.x + threadIdx.x;
    const int total = 2 * B * (blockIdx.y ? M : N);  // N==M here; keep simple
    (void)total;
    // gid decomposes over [2][B][Nq]; N==M==Nq assumed equal per dir slice
    const int NqN = N, NqM = M;
    const int perDir0 = B * NqN, perDir1 = B * NqM;
    int dir, rem;
    if (gid < perDir0) { dir = 0; rem = gid; }
    else if (gid < perDir0 + perDir1) { dir = 1; rem = gid - perDir0; }
    else return;
    const int Nq = dir ? NqM : NqN;
    const int b = rem / Nq, i = rem % Nq;

    const size_t base = ((size_t)(dir * B + b) * S) * Nq + i;
    float bdv = INFINITY;
    int   biv = 0;
    for (int sp = 0; sp < S; ++sp) {         // ascending split order: strict <
        float d = pd[base + (size_t)sp * Nq]; // keeps first occurrence
        if (d < bdv) { bdv = d; biv = pi[base + (size_t)sp * Nq]; }
    }

    float* dist_out = out + (dir ? (size_t)B * N : 0);
    float* idx_out  = out + (size_t)B * N + (size_t)B * M + (dir ? (size_t)B * N : 0);
    dist_out[(size_t)b * Nq + i] = bdv;
    idx_out[(size_t)b * Nq + i]  = (float)biv;
}

extern "C" void kernel_launch(void* const* d_in, const int* in_sizes, int n_in,
                              void* d_out, int out_size, void* d_ws, size_t ws_size,
                              hipStream_t stream) {
    const float* xyz1 = (const float*)d_in[0];
    const float* xyz2 = (const float*)d_in[1];
    float* out = (float*)d_out;
    const int B = 4;
    const int N = in_sizes[0] / (B * 3);
    const int M = in_sizes[1] / (B * 3);
    const int NQ = (N > M ? N : M);
    const int NR = (N > M ? N : M);

    // pick split count S (pow2) such that partials fit in ws: 2*B*S*NQ*8 bytes
    int S = 16;
    while (S > 1 && (size_t)2 * B * S * NQ * 8 > ws_size) S >>= 1;
    while (NR % S) S >>= 1;  // require exact divisibility
    const int C = NR / S;

    float* pd = (float*)d_ws;
    int*   pi = (int*)((char*)d_ws + (size_t)2 * B * S * NQ * 4);

    dim3 grid((NQ + QPB - 1) / QPB, B * S, 2);
    size_t lds = (size_t)C * 3 * sizeof(float);
    chamfer_main<<<grid, dim3(BLK, 1, 1), lds, stream>>>(
        xyz1, xyz2, pd, pi, N, M, B, S, C);

    int totalOut = 2 * B * NQ;
    chamfer_merge<<<dim3((totalOut + 255) / 256, 1, 1), dim3(256, 1, 1), 0, stream>>>(
        pd, pi, out, N, M, B, S);
}